// Round 1
// baseline (971.952 us; speedup 1.0000x reference)
//
#include <hip/hip_runtime.h>

#define F_IN 128
#define F_ALL 128   // concat of two 64-wide hops
#define F_HOP 64

// ---------------------------------------------------------------- zero fill
__global__ __launch_bounds__(256) void zero_kernel(float4* __restrict__ p, int n4) {
    int i = blockIdx.x * 256 + threadIdx.x;
    if (i < n4) p[i] = make_float4(0.f, 0.f, 0.f, 0.f);
}

// ---------------------------------------------------------------- GEMM
// H[n][0:64] = x[n] @ W0 ; H[n][64:128] = x[n] @ W1
// block = 256 threads, 32 rows x 128 cols per block, 4x4 register tile.
// x tile transposed in LDS (stride 36 floats, 16B-aligned quads);
// W rows streamed from global (64KB total -> L1/L2 resident, broadcast reads).
__global__ __launch_bounds__(256) void gemm_kernel(
    const float* __restrict__ x, const float* __restrict__ W0,
    const float* __restrict__ W1, float* __restrict__ H, int N) {
    __shared__ float xT[128 * 36];
    const int tid = threadIdx.x;
    const int rbase = blockIdx.x * 32;
    {
        const int k  = tid & 127;
        const int rr = tid >> 7;          // 0..1
        #pragma unroll
        for (int i = 0; i < 32; i += 2) {
            const int r = rbase + i + rr;
            xT[k * 36 + i + rr] = (r < N) ? x[(size_t)r * F_IN + k] : 0.f;
        }
    }
    __syncthreads();
    const int jg = tid & 31;              // 32 col-quads -> 128 cols
    const int rg = tid >> 5;              // 8 row-quads  -> 32 rows
    const float* Wp = (jg < 16) ? (W0 + 4 * jg) : (W1 + 4 * (jg - 16));
    float acc[4][4] = {};
    #pragma unroll 4
    for (int k = 0; k < 128; ++k) {
        const float4 w  = *(const float4*)(Wp + (size_t)k * F_HOP);
        const float4 xv = *(const float4*)(&xT[k * 36 + 4 * rg]);
        acc[0][0] += xv.x * w.x; acc[0][1] += xv.x * w.y; acc[0][2] += xv.x * w.z; acc[0][3] += xv.x * w.w;
        acc[1][0] += xv.y * w.x; acc[1][1] += xv.y * w.y; acc[1][2] += xv.y * w.z; acc[1][3] += xv.y * w.w;
        acc[2][0] += xv.z * w.x; acc[2][1] += xv.z * w.y; acc[2][2] += xv.z * w.z; acc[2][3] += xv.z * w.w;
        acc[3][0] += xv.w * w.x; acc[3][1] += xv.w * w.y; acc[3][2] += xv.w * w.z; acc[3][3] += xv.w * w.w;
    }
    const int jbase = 4 * jg;
    #pragma unroll
    for (int i = 0; i < 4; ++i) {
        const int r = rbase + 4 * rg + i;
        if (r < N)
            *(float4*)(&H[(size_t)r * F_ALL + jbase]) =
                make_float4(acc[i][0], acc[i][1], acc[i][2], acc[i][3]);
    }
}

// ---------------------------------------------------------------- SpMM
// OUT[r][f] += val * V[c*vstride + f]   (F lanes per edge, atomic scatter)
template <int F>
__global__ __launch_bounds__(256) void spmm_kernel(
    const int* __restrict__ ei, const float* __restrict__ ea,
    const float* __restrict__ V, int vstride, float* __restrict__ OUT, int E) {
    const int idx = blockIdx.x * 256 + threadIdx.x;
    const int e = idx / F;                 // F is a power of two -> shift
    const int f = threadIdx.x & (F - 1);
    if (e >= E) return;
    const int r = ei[e];
    const int c = ei[E + e];
    const float v = ea[e];
    atomicAdd(&OUT[(size_t)r * F + f], v * V[(size_t)c * vstride + f]);
}

__global__ __launch_bounds__(256) void deg1_kernel(
    const int* __restrict__ ei, const float* __restrict__ ea,
    float* __restrict__ deg, int E) {
    const int e = blockIdx.x * 256 + threadIdx.x;
    if (e < E) atomicAdd(&deg[ei[e]], ea[e]);
}

__global__ __launch_bounds__(256) void deg2_kernel(
    const int* __restrict__ ei, const float* __restrict__ ea,
    const float* __restrict__ d1, float* __restrict__ d2, int E) {
    const int e = blockIdx.x * 256 + threadIdx.x;
    if (e < E) atomicAdd(&d2[ei[e]], ea[e] * d1[ei[E + e]]);
}

// ---------------------------------------------------------------- epilogue
// one wave per node: y = agg/deg + b ; enc = relu(y) + sigmoid(y.fc+bf)*min(y,0)
__global__ __launch_bounds__(256) void epilogue_kernel(
    const float* __restrict__ AGG1, const float* __restrict__ T,
    const float* __restrict__ d1, const float* __restrict__ d2,
    const float* __restrict__ b0, const float* __restrict__ b1,
    const float* __restrict__ fc0, const float* __restrict__ fc1,
    const float* __restrict__ bf0, const float* __restrict__ bf1,
    float* __restrict__ out, int N) {
    const int n = blockIdx.x * 4 + (threadIdx.x >> 6);
    const int f = threadIdx.x & 63;
    if (n >= N) return;

    // hop 0
    {
        const float dg = d1[n];
        const float a  = AGG1[(size_t)n * F_ALL + f];
        float y = (dg > 0.f) ? a / dg : 0.f;
        y += b0[f];
        float t = y * fc0[f];
        #pragma unroll
        for (int m = 1; m < 64; m <<= 1) t += __shfl_xor(t, m, 64);
        const float g = 1.f / (1.f + __expf(-(t + bf0[0])));
        const float e = (y < 0.f ? 0.f : y) + g * (y > 0.f ? 0.f : y);
        out[(size_t)n * F_ALL + f] = e;
    }
    // hop 1
    {
        const float dg = d2[n];
        const float a  = T[(size_t)n * F_HOP + f];
        float y = (dg > 0.f) ? a / dg : 0.f;
        y += b1[f];
        float t = y * fc1[f];
        #pragma unroll
        for (int m = 1; m < 64; m <<= 1) t += __shfl_xor(t, m, 64);
        const float g = 1.f / (1.f + __expf(-(t + bf1[0])));
        const float e = (y < 0.f ? 0.f : y) + g * (y > 0.f ? 0.f : y);
        out[(size_t)n * F_ALL + F_HOP + f] = e;
    }
}

// ---------------------------------------------------------------- launch
extern "C" void kernel_launch(void* const* d_in, const int* in_sizes, int n_in,
                              void* d_out, int out_size, void* d_ws, size_t ws_size,
                              hipStream_t stream) {
    const float* x   = (const float*)d_in[0];
    const int*   ei  = (const int*)  d_in[1];
    const float* ea  = (const float*)d_in[2];
    const float* W0  = (const float*)d_in[3];
    const float* b0  = (const float*)d_in[4];
    const float* W1  = (const float*)d_in[5];
    const float* b1  = (const float*)d_in[6];
    const float* fc0 = (const float*)d_in[7];
    const float* bf0 = (const float*)d_in[8];
    const float* fc1 = (const float*)d_in[9];
    const float* bf1 = (const float*)d_in[10];
    float* out = (float*)d_out;

    const int N = in_sizes[0] / F_IN;
    const int E = in_sizes[2];

    // workspace layout (floats)
    float* H    = (float*)d_ws;          // N*128
    float* AGG1 = H    + (size_t)N * F_ALL;   // N*128  (zeroed)
    float* T    = AGG1 + (size_t)N * F_ALL;   // N*64   (zeroed)
    float* dg1  = T    + (size_t)N * F_HOP;   // N      (zeroed)
    float* dg2  = dg1  + (size_t)N;           // N      (zeroed)

    // zero AGG1..dg2 (contiguous)
    {
        const size_t nf = (size_t)N * F_ALL + (size_t)N * F_HOP + 2 * (size_t)N;
        const int n4 = (int)((nf + 3) >> 2);
        zero_kernel<<<(n4 + 255) / 256, 256, 0, stream>>>((float4*)AGG1, n4);
    }

    // H = x @ [W0|W1]
    gemm_kernel<<<(N + 31) / 32, 256, 0, stream>>>(x, W0, W1, H, N);

    // degrees
    deg1_kernel<<<(E + 255) / 256, 256, 0, stream>>>(ei, ea, dg1, E);

    // AGG1 = A * H  (128-wide)
    spmm_kernel<128><<<(int)(((size_t)E * 128 + 255) / 256), 256, 0, stream>>>(
        ei, ea, H, F_ALL, AGG1, E);

    // dg2 = A * dg1
    deg2_kernel<<<(E + 255) / 256, 256, 0, stream>>>(ei, ea, dg1, dg2, E);

    // T = A * AGG1[:, 64:128]  (64-wide)
    spmm_kernel<64><<<(int)(((size_t)E * 64 + 255) / 256), 256, 0, stream>>>(
        ei, ea, AGG1 + F_HOP, F_ALL, T, E);

    // epilogue
    epilogue_kernel<<<(N + 3) / 4, 256, 0, stream>>>(
        AGG1, T, dg1, dg2, b0, b1, fc0, fc1, bf0, bf1, out, N);
}

// Round 2
// 453.464 us; speedup vs baseline: 2.1434x; 2.1434x over previous
//
#include <hip/hip_runtime.h>

#define F_IN 128
#define F_ALL 128
#define F_HOP 64

// ---------------------------------------------------------------- zero fill (ints)
__global__ __launch_bounds__(256) void zero_i4_kernel(int4* __restrict__ p, int n4) {
    int i = blockIdx.x * 256 + threadIdx.x;
    if (i < n4) p[i] = make_int4(0, 0, 0, 0);
}

// ---------------------------------------------------------------- GEMM
// H[n][0:64] = x[n] @ W0 ; H[n][64:128] = x[n] @ W1
__global__ __launch_bounds__(256) void gemm_kernel(
    const float* __restrict__ x, const float* __restrict__ W0,
    const float* __restrict__ W1, float* __restrict__ H, int N) {
    __shared__ float xT[128 * 36];
    const int tid = threadIdx.x;
    const int rbase = blockIdx.x * 32;
    {
        const int k  = tid & 127;
        const int rr = tid >> 7;
        #pragma unroll
        for (int i = 0; i < 32; i += 2) {
            const int r = rbase + i + rr;
            xT[k * 36 + i + rr] = (r < N) ? x[(size_t)r * F_IN + k] : 0.f;
        }
    }
    __syncthreads();
    const int jg = tid & 31;
    const int rg = tid >> 5;
    const float* Wp = (jg < 16) ? (W0 + 4 * jg) : (W1 + 4 * (jg - 16));
    float acc[4][4] = {};
    #pragma unroll 4
    for (int k = 0; k < 128; ++k) {
        const float4 w  = *(const float4*)(Wp + (size_t)k * F_HOP);
        const float4 xv = *(const float4*)(&xT[k * 36 + 4 * rg]);
        acc[0][0] += xv.x * w.x; acc[0][1] += xv.x * w.y; acc[0][2] += xv.x * w.z; acc[0][3] += xv.x * w.w;
        acc[1][0] += xv.y * w.x; acc[1][1] += xv.y * w.y; acc[1][2] += xv.y * w.z; acc[1][3] += xv.y * w.w;
        acc[2][0] += xv.z * w.x; acc[2][1] += xv.z * w.y; acc[2][2] += xv.z * w.z; acc[2][3] += xv.z * w.w;
        acc[3][0] += xv.w * w.x; acc[3][1] += xv.w * w.y; acc[3][2] += xv.w * w.z; acc[3][3] += xv.w * w.w;
    }
    const int jbase = 4 * jg;
    #pragma unroll
    for (int i = 0; i < 4; ++i) {
        const int r = rbase + 4 * rg + i;
        if (r < N)
            *(float4*)(&H[(size_t)r * F_ALL + jbase]) =
                make_float4(acc[i][0], acc[i][1], acc[i][2], acc[i][3]);
    }
}

// ---------------------------------------------------------------- CSR build
__global__ __launch_bounds__(256) void count_kernel(
    const int* __restrict__ ei, int* __restrict__ cnt, int E) {
    const int e = blockIdx.x * 256 + threadIdx.x;
    if (e < E) atomicAdd(&cnt[ei[e]], 1);
}

// phase A: per-block (1024 ints) reduction -> part[blk]
__global__ __launch_bounds__(256) void reduce_kernel(
    const int* __restrict__ cnt, int* __restrict__ part) {
    __shared__ int ws[4];
    const int t = threadIdx.x;
    const int4 c = *(const int4*)(cnt + blockIdx.x * 1024 + t * 4);
    int s = c.x + c.y + c.z + c.w;
    #pragma unroll
    for (int m = 1; m < 64; m <<= 1) s += __shfl_xor(s, m, 64);
    if ((t & 63) == 0) ws[t >> 6] = s;
    __syncthreads();
    if (t == 0) part[blockIdx.x] = ws[0] + ws[1] + ws[2] + ws[3];
}

// phase B: single-thread exclusive scan of B partials; also rowptr[N]=E
__global__ void scan_partials_kernel(const int* __restrict__ part,
                                     int* __restrict__ poff,
                                     int* __restrict__ rowptr, int B, int N) {
    if (threadIdx.x == 0 && blockIdx.x == 0) {
        int acc = 0;
        for (int i = 0; i < B; ++i) { poff[i] = acc; acc += part[i]; }
        rowptr[N] = acc;
    }
}

// phase C: block-local exclusive scan + block offset -> rowptr & next
__global__ __launch_bounds__(256) void scan_apply_kernel(
    const int* __restrict__ cnt, const int* __restrict__ poff,
    int* __restrict__ rowptr, int* __restrict__ next, int N) {
    __shared__ int wsum[4];
    const int t = threadIdx.x;
    const int base = blockIdx.x * 1024 + t * 4;
    const int4 c = *(const int4*)(cnt + base);
    const int s = c.x + c.y + c.z + c.w;
    const int lane = t & 63;
    int v = s;
    #pragma unroll
    for (int d = 1; d < 64; d <<= 1) {
        int u = __shfl_up(v, (unsigned)d, 64);
        if (lane >= d) v += u;
    }
    const int w = t >> 6;
    if (lane == 63) wsum[w] = v;
    __syncthreads();
    int woff = 0;
    #pragma unroll
    for (int i = 0; i < 4; ++i) if (i < w) woff += wsum[i];
    const int excl = poff[blockIdx.x] + woff + (v - s);
    const int o0 = excl, o1 = o0 + c.x, o2 = o1 + c.y, o3 = o2 + c.z;
    if (base + 3 < N) {
        *(int4*)(rowptr + base) = make_int4(o0, o1, o2, o3);
        *(int4*)(next   + base) = make_int4(o0, o1, o2, o3);
    } else {
        if (base + 0 < N) { rowptr[base + 0] = o0; next[base + 0] = o0; }
        if (base + 1 < N) { rowptr[base + 1] = o1; next[base + 1] = o1; }
        if (base + 2 < N) { rowptr[base + 2] = o2; next[base + 2] = o2; }
        if (base + 3 < N) { rowptr[base + 3] = o3; next[base + 3] = o3; }
    }
}

__global__ __launch_bounds__(256) void scatter_kernel(
    const int* __restrict__ ei, const float* __restrict__ ea,
    int* __restrict__ next, int* __restrict__ col_s,
    float* __restrict__ val_s, int E) {
    const int e = blockIdx.x * 256 + threadIdx.x;
    if (e >= E) return;
    const int r = ei[e];
    const int pos = atomicAdd(&next[r], 1);
    col_s[pos] = ei[E + e];
    val_s[pos] = ea[e];
}

// ---------------------------------------------------------------- pass 1
// one wave per row: acc = sum val*H[col], d = sum val.
// writes out[:,0:64] (fused epilogue hop0), T_in (raw hop1 partial), dg1.
__global__ __launch_bounds__(256) void pass1_kernel(
    const int* __restrict__ rowptr, const int* __restrict__ col_s,
    const float* __restrict__ val_s, const float* __restrict__ H,
    const float* __restrict__ b0, const float* __restrict__ fc0,
    const float* __restrict__ bf0,
    float* __restrict__ out, float* __restrict__ T_in,
    float* __restrict__ dg1, int N) {
    int r = blockIdx.x * 4 + (threadIdx.x >> 6);
    r = __builtin_amdgcn_readfirstlane(r);
    if (r >= N) return;
    const int f = threadIdx.x & 63;
    const int jb = rowptr[r], je = rowptr[r + 1];
    float acc0 = 0.f, acc1 = 0.f, d = 0.f;
    for (int j = jb; j < je; ++j) {
        const int   c = col_s[j];
        const float v = val_s[j];
        const float* hp = H + (size_t)c * F_ALL;
        d    += v;
        acc0 += v * hp[f];
        acc1 += v * hp[f + 64];
    }
    T_in[(size_t)r * F_HOP + f] = acc1;
    if (f == 0) dg1[r] = d;
    float y = (d > 0.f ? acc0 / d : 0.f) + b0[f];
    float t = y * fc0[f];
    #pragma unroll
    for (int m = 1; m < 64; m <<= 1) t += __shfl_xor(t, m, 64);
    const float g = 1.f / (1.f + __expf(-(t + bf0[0])));
    out[(size_t)r * F_ALL + f] = fmaxf(y, 0.f) + g * fminf(y, 0.f);
}

// ---------------------------------------------------------------- pass 2
// one wave per row: acc = sum val*T_in[col], d2 = sum val*dg1[col].
// writes out[:,64:128] (fused epilogue hop1).
__global__ __launch_bounds__(256) void pass2_kernel(
    const int* __restrict__ rowptr, const int* __restrict__ col_s,
    const float* __restrict__ val_s, const float* __restrict__ T_in,
    const float* __restrict__ dg1,
    const float* __restrict__ b1, const float* __restrict__ fc1,
    const float* __restrict__ bf1,
    float* __restrict__ out, int N) {
    int r = blockIdx.x * 4 + (threadIdx.x >> 6);
    r = __builtin_amdgcn_readfirstlane(r);
    if (r >= N) return;
    const int f = threadIdx.x & 63;
    const int jb = rowptr[r], je = rowptr[r + 1];
    float acc = 0.f, d2 = 0.f;
    for (int j = jb; j < je; ++j) {
        const int   c = col_s[j];
        const float v = val_s[j];
        d2  += v * dg1[c];
        acc += v * T_in[(size_t)c * F_HOP + f];
    }
    float y = (d2 > 0.f ? acc / d2 : 0.f) + b1[f];
    float t = y * fc1[f];
    #pragma unroll
    for (int m = 1; m < 64; m <<= 1) t += __shfl_xor(t, m, 64);
    const float g = 1.f / (1.f + __expf(-(t + bf1[0])));
    out[(size_t)r * F_ALL + F_HOP + f] = fmaxf(y, 0.f) + g * fminf(y, 0.f);
}

// ---------------------------------------------------------------- launch
extern "C" void kernel_launch(void* const* d_in, const int* in_sizes, int n_in,
                              void* d_out, int out_size, void* d_ws, size_t ws_size,
                              hipStream_t stream) {
    const float* x   = (const float*)d_in[0];
    const int*   ei  = (const int*)  d_in[1];
    const float* ea  = (const float*)d_in[2];
    const float* W0  = (const float*)d_in[3];
    const float* b0  = (const float*)d_in[4];
    const float* W1  = (const float*)d_in[5];
    const float* b1  = (const float*)d_in[6];
    const float* fc0 = (const float*)d_in[7];
    const float* bf0 = (const float*)d_in[8];
    const float* fc1 = (const float*)d_in[9];
    const float* bf1 = (const float*)d_in[10];
    float* out = (float*)d_out;

    const int N = in_sizes[0] / F_IN;
    const int E = in_sizes[2];
    const int B = (N + 1023) / 1024;        // scan blocks (1024 counts each)

    // workspace layout (all 4-byte elements, regions padded to 16B)
    float* H      = (float*)d_ws;                       // N*128
    float* T_in   = H    + (size_t)N * F_ALL;           // N*64
    float* dg1    = T_in + (size_t)N * F_HOP;           // N
    float* val_s  = dg1  + (size_t)((N + 3) & ~3);      // E
    int*   col_s  = (int*)(val_s + (size_t)((E + 3) & ~3));       // E
    int*   cnt    = col_s + (size_t)((E + 3) & ~3);     // B*1024 (zeroed)
    int*   rowptr = cnt + (size_t)B * 1024;             // N+1
    int*   next   = rowptr + (size_t)((N + 7) & ~3);    // N
    int*   part   = next + (size_t)((N + 3) & ~3);      // B
    int*   poff   = part + (size_t)((B + 3) & ~3);      // B

    // GEMM (independent of CSR build)
    gemm_kernel<<<(N + 31) / 32, 256, 0, stream>>>(x, W0, W1, H, N);

    // zero cnt (B*1024 ints)
    zero_i4_kernel<<<(B * 1024 / 4 + 255) / 256, 256, 0, stream>>>((int4*)cnt, B * 1024 / 4);

    // CSR build: histogram -> scan -> scatter
    count_kernel<<<(E + 255) / 256, 256, 0, stream>>>(ei, cnt, E);
    reduce_kernel<<<B, 256, 0, stream>>>(cnt, part);
    scan_partials_kernel<<<1, 64, 0, stream>>>(part, poff, rowptr, B, N);
    scan_apply_kernel<<<B, 256, 0, stream>>>(cnt, poff, rowptr, next, N);
    scatter_kernel<<<(E + 255) / 256, 256, 0, stream>>>(ei, ea, next, col_s, val_s, E);

    // pass 1: out[:,0:64], T_in, dg1
    pass1_kernel<<<(N + 3) / 4, 256, 0, stream>>>(
        rowptr, col_s, val_s, H, b0, fc0, bf0, out, T_in, dg1, N);

    // pass 2: out[:,64:128]
    pass2_kernel<<<(N + 3) / 4, 256, 0, stream>>>(
        rowptr, col_s, val_s, T_in, dg1, b1, fc1, bf1, out, N);
}

// Round 3
// 382.179 us; speedup vs baseline: 2.5432x; 1.1865x over previous
//
#include <hip/hip_runtime.h>

#define F_IN 128
#define F_ALL 128
#define F_HOP 64

typedef unsigned int uint;

// ---------------------------------------------------------------- helpers
__device__ __forceinline__ uint pack_bf16(float lo, float hi) {
    uint ul = __float_as_uint(lo), uh = __float_as_uint(hi);
    ul += 0x7FFFu + ((ul >> 16) & 1u);
    uh += 0x7FFFu + ((uh >> 16) & 1u);
    return (ul >> 16) | (uh & 0xFFFF0000u);
}
__device__ __forceinline__ float bf_lo(uint h) { return __uint_as_float(h << 16); }
__device__ __forceinline__ float bf_hi(uint h) { return __uint_as_float(h & 0xFFFF0000u); }
__device__ __forceinline__ unsigned short to_bf16(float x) {
    uint u = __float_as_uint(x);
    u += 0x7FFFu + ((u >> 16) & 1u);
    return (unsigned short)(u >> 16);
}

// ---------------------------------------------------------------- zero fill (ints)
__global__ __launch_bounds__(256) void zero_i4_kernel(int4* __restrict__ p, int n4) {
    int i = blockIdx.x * 256 + threadIdx.x;
    if (i < n4) p[i] = make_int4(0, 0, 0, 0);
}

// ---------------------------------------------------------------- GEMM + bf16 pack
// H2[r][f] = pack(bf16((x@W0)[r][f]), bf16((x@W1)[r][f])), f in 0..63.
// block: 64 rows x 64 packed cols, 256 threads, 4x4x2 register tile.
__global__ __launch_bounds__(256) void gemm_pack_kernel(
    const float* __restrict__ x, const float* __restrict__ W0,
    const float* __restrict__ W1, uint* __restrict__ H2, int N) {
    __shared__ float xT[128 * 68];
    const int tid = threadIdx.x;
    const int rbase = blockIdx.x * 64;
    {
        const int r  = tid >> 2;          // 0..63
        const int kq = (tid & 3) * 4;     // 0,4,8,12
        const int gr = rbase + r;
        #pragma unroll
        for (int kk = 0; kk < 128; kk += 16) {
            float4 xv = make_float4(0.f, 0.f, 0.f, 0.f);
            if (gr < N) xv = *(const float4*)(x + (size_t)gr * F_IN + kk + kq);
            const int k = kk + kq;
            xT[(k + 0) * 68 + r] = xv.x;
            xT[(k + 1) * 68 + r] = xv.y;
            xT[(k + 2) * 68 + r] = xv.z;
            xT[(k + 3) * 68 + r] = xv.w;
        }
    }
    __syncthreads();
    const int jg = tid & 15;              // col-quad (cols 4jg..4jg+3)
    const int rg = tid >> 4;              // row-quad (rows 4rg..4rg+3)
    float a0[4][4] = {}, a1[4][4] = {};
    #pragma unroll 4
    for (int k = 0; k < 128; ++k) {
        const float4 w0 = *(const float4*)(W0 + (size_t)k * F_HOP + 4 * jg);
        const float4 w1 = *(const float4*)(W1 + (size_t)k * F_HOP + 4 * jg);
        const float4 xv = *(const float4*)(&xT[k * 68 + 4 * rg]);
        const float xr[4] = {xv.x, xv.y, xv.z, xv.w};
        #pragma unroll
        for (int i = 0; i < 4; ++i) {
            a0[i][0] += xr[i] * w0.x; a0[i][1] += xr[i] * w0.y;
            a0[i][2] += xr[i] * w0.z; a0[i][3] += xr[i] * w0.w;
            a1[i][0] += xr[i] * w1.x; a1[i][1] += xr[i] * w1.y;
            a1[i][2] += xr[i] * w1.z; a1[i][3] += xr[i] * w1.w;
        }
    }
    #pragma unroll
    for (int i = 0; i < 4; ++i) {
        const int r = rbase + 4 * rg + i;
        if (r < N) {
            uint4 o;
            o.x = pack_bf16(a0[i][0], a1[i][0]);
            o.y = pack_bf16(a0[i][1], a1[i][1]);
            o.z = pack_bf16(a0[i][2], a1[i][2]);
            o.w = pack_bf16(a0[i][3], a1[i][3]);
            *(uint4*)(H2 + (size_t)r * F_HOP + 4 * jg) = o;
        }
    }
}

// ---------------------------------------------------------------- CSR build
__global__ __launch_bounds__(256) void count_kernel(
    const int* __restrict__ ei, int* __restrict__ cnt, int E) {
    const int e = blockIdx.x * 256 + threadIdx.x;
    if (e < E) atomicAdd(&cnt[ei[e]], 1);
}

__global__ __launch_bounds__(256) void reduce_kernel(
    const int* __restrict__ cnt, int* __restrict__ part) {
    __shared__ int ws[4];
    const int t = threadIdx.x;
    const int4 c = *(const int4*)(cnt + blockIdx.x * 1024 + t * 4);
    int s = c.x + c.y + c.z + c.w;
    #pragma unroll
    for (int m = 1; m < 64; m <<= 1) s += __shfl_xor(s, m, 64);
    if ((t & 63) == 0) ws[t >> 6] = s;
    __syncthreads();
    if (t == 0) part[blockIdx.x] = ws[0] + ws[1] + ws[2] + ws[3];
}

__global__ void scan_partials_kernel(const int* __restrict__ part,
                                     int* __restrict__ poff,
                                     int* __restrict__ rowptr, int B, int N) {
    if (threadIdx.x == 0 && blockIdx.x == 0) {
        int acc = 0;
        for (int i = 0; i < B; ++i) { poff[i] = acc; acc += part[i]; }
        rowptr[N] = acc;
    }
}

__global__ __launch_bounds__(256) void scan_apply_kernel(
    const int* __restrict__ cnt, const int* __restrict__ poff,
    int* __restrict__ rowptr, int* __restrict__ next, int N) {
    __shared__ int wsum[4];
    const int t = threadIdx.x;
    const int base = blockIdx.x * 1024 + t * 4;
    const int4 c = *(const int4*)(cnt + base);
    const int s = c.x + c.y + c.z + c.w;
    const int lane = t & 63;
    int v = s;
    #pragma unroll
    for (int d = 1; d < 64; d <<= 1) {
        int u = __shfl_up(v, (unsigned)d, 64);
        if (lane >= d) v += u;
    }
    const int w = t >> 6;
    if (lane == 63) wsum[w] = v;
    __syncthreads();
    int woff = 0;
    #pragma unroll
    for (int i = 0; i < 4; ++i) if (i < w) woff += wsum[i];
    const int excl = poff[blockIdx.x] + woff + (v - s);
    const int o0 = excl, o1 = o0 + c.x, o2 = o1 + c.y, o3 = o2 + c.z;
    if (base + 3 < N) {
        *(int4*)(rowptr + base) = make_int4(o0, o1, o2, o3);
        *(int4*)(next   + base) = make_int4(o0, o1, o2, o3);
    } else {
        if (base + 0 < N) { rowptr[base + 0] = o0; next[base + 0] = o0; }
        if (base + 1 < N) { rowptr[base + 1] = o1; next[base + 1] = o1; }
        if (base + 2 < N) { rowptr[base + 2] = o2; next[base + 2] = o2; }
        if (base + 3 < N) { rowptr[base + 3] = o3; next[base + 3] = o3; }
    }
}

__global__ __launch_bounds__(256) void scatter_kernel(
    const int* __restrict__ ei, const float* __restrict__ ea,
    int* __restrict__ next, int2* __restrict__ ecv, int E) {
    const int e = blockIdx.x * 256 + threadIdx.x;
    if (e >= E) return;
    const int r = ei[e];
    const int pos = atomicAdd(&next[r], 1);
    ecv[pos] = make_int2(ei[E + e], __float_as_int(ea[e]));
}

// ---------------------------------------------------------------- pass 1
// one wave per row, x4 unrolled edge loop. H2 packed bf16 (both hops).
__global__ __launch_bounds__(256) void pass1_kernel(
    const int* __restrict__ rowptr, const int2* __restrict__ ecv,
    const uint* __restrict__ H2,
    const float* __restrict__ b0, const float* __restrict__ fc0,
    const float* __restrict__ bf0,
    float* __restrict__ out, unsigned short* __restrict__ T16,
    float* __restrict__ dg1, int N) {
    int r = blockIdx.x * 4 + (threadIdx.x >> 6);
    r = __builtin_amdgcn_readfirstlane(r);
    if (r >= N) return;
    const int f = threadIdx.x & 63;
    const int jb = rowptr[r], je = rowptr[r + 1];
    float s0a = 0.f, s0b = 0.f, s0c = 0.f, s0d = 0.f;
    float s1a = 0.f, s1b = 0.f, s1c = 0.f, s1d = 0.f;
    float da = 0.f, db = 0.f;
    int j = jb;
    for (; j + 4 <= je; j += 4) {
        const int2 e0 = ecv[j], e1 = ecv[j + 1], e2 = ecv[j + 2], e3 = ecv[j + 3];
        const uint h0 = H2[(size_t)e0.x * F_HOP + f];
        const uint h1 = H2[(size_t)e1.x * F_HOP + f];
        const uint h2 = H2[(size_t)e2.x * F_HOP + f];
        const uint h3 = H2[(size_t)e3.x * F_HOP + f];
        const float v0 = __int_as_float(e0.y), v1 = __int_as_float(e1.y);
        const float v2 = __int_as_float(e2.y), v3 = __int_as_float(e3.y);
        da += v0 + v1; db += v2 + v3;
        s0a = fmaf(v0, bf_lo(h0), s0a); s1a = fmaf(v0, bf_hi(h0), s1a);
        s0b = fmaf(v1, bf_lo(h1), s0b); s1b = fmaf(v1, bf_hi(h1), s1b);
        s0c = fmaf(v2, bf_lo(h2), s0c); s1c = fmaf(v2, bf_hi(h2), s1c);
        s0d = fmaf(v3, bf_lo(h3), s0d); s1d = fmaf(v3, bf_hi(h3), s1d);
    }
    for (; j < je; ++j) {
        const int2 e0 = ecv[j];
        const uint h0 = H2[(size_t)e0.x * F_HOP + f];
        const float v0 = __int_as_float(e0.y);
        da += v0;
        s0a = fmaf(v0, bf_lo(h0), s0a); s1a = fmaf(v0, bf_hi(h0), s1a);
    }
    const float acc0 = (s0a + s0b) + (s0c + s0d);
    const float acc1 = (s1a + s1b) + (s1c + s1d);
    const float d = (da + db);
    T16[(size_t)r * F_HOP + f] = to_bf16(acc1);
    if (f == 0) dg1[r] = d;
    float y = (d > 0.f ? acc0 / d : 0.f) + b0[f];
    float t = y * fc0[f];
    #pragma unroll
    for (int m = 1; m < 64; m <<= 1) t += __shfl_xor(t, m, 64);
    const float g = 1.f / (1.f + __expf(-(t + bf0[0])));
    out[(size_t)r * F_ALL + f] = fmaxf(y, 0.f) + g * fminf(y, 0.f);
}

// ---------------------------------------------------------------- pass 2
__global__ __launch_bounds__(256) void pass2_kernel(
    const int* __restrict__ rowptr, const int2* __restrict__ ecv,
    const unsigned short* __restrict__ T16, const float* __restrict__ dg1,
    const float* __restrict__ b1, const float* __restrict__ fc1,
    const float* __restrict__ bf1,
    float* __restrict__ out, int N) {
    int r = blockIdx.x * 4 + (threadIdx.x >> 6);
    r = __builtin_amdgcn_readfirstlane(r);
    if (r >= N) return;
    const int f = threadIdx.x & 63;
    const int jb = rowptr[r], je = rowptr[r + 1];
    float sa = 0.f, sb = 0.f, sc = 0.f, sd = 0.f;
    float da = 0.f, db = 0.f;
    int j = jb;
    for (; j + 4 <= je; j += 4) {
        const int2 e0 = ecv[j], e1 = ecv[j + 1], e2 = ecv[j + 2], e3 = ecv[j + 3];
        const unsigned short t0 = T16[(size_t)e0.x * F_HOP + f];
        const unsigned short t1 = T16[(size_t)e1.x * F_HOP + f];
        const unsigned short t2 = T16[(size_t)e2.x * F_HOP + f];
        const unsigned short t3 = T16[(size_t)e3.x * F_HOP + f];
        const float g0 = dg1[e0.x], g1 = dg1[e1.x], g2 = dg1[e2.x], g3 = dg1[e3.x];
        const float v0 = __int_as_float(e0.y), v1 = __int_as_float(e1.y);
        const float v2 = __int_as_float(e2.y), v3 = __int_as_float(e3.y);
        da = fmaf(v0, g0, da); db = fmaf(v1, g1, db);
        da = fmaf(v2, g2, da); db = fmaf(v3, g3, db);
        sa = fmaf(v0, __uint_as_float((uint)t0 << 16), sa);
        sb = fmaf(v1, __uint_as_float((uint)t1 << 16), sb);
        sc = fmaf(v2, __uint_as_float((uint)t2 << 16), sc);
        sd = fmaf(v3, __uint_as_float((uint)t3 << 16), sd);
    }
    for (; j < je; ++j) {
        const int2 e0 = ecv[j];
        const unsigned short t0 = T16[(size_t)e0.x * F_HOP + f];
        const float v0 = __int_as_float(e0.y);
        da = fmaf(v0, dg1[e0.x], da);
        sa = fmaf(v0, __uint_as_float((uint)t0 << 16), sa);
    }
    const float acc = (sa + sb) + (sc + sd);
    const float d2 = da + db;
    float y = (d2 > 0.f ? acc / d2 : 0.f) + b1[f];
    float t = y * fc1[f];
    #pragma unroll
    for (int m = 1; m < 64; m <<= 1) t += __shfl_xor(t, m, 64);
    const float g = 1.f / (1.f + __expf(-(t + bf1[0])));
    out[(size_t)r * F_ALL + F_HOP + f] = fmaxf(y, 0.f) + g * fminf(y, 0.f);
}

// ---------------------------------------------------------------- launch
extern "C" void kernel_launch(void* const* d_in, const int* in_sizes, int n_in,
                              void* d_out, int out_size, void* d_ws, size_t ws_size,
                              hipStream_t stream) {
    const float* x   = (const float*)d_in[0];
    const int*   ei  = (const int*)  d_in[1];
    const float* ea  = (const float*)d_in[2];
    const float* W0  = (const float*)d_in[3];
    const float* b0  = (const float*)d_in[4];
    const float* W1  = (const float*)d_in[5];
    const float* b1  = (const float*)d_in[6];
    const float* fc0 = (const float*)d_in[7];
    const float* bf0 = (const float*)d_in[8];
    const float* fc1 = (const float*)d_in[9];
    const float* bf1 = (const float*)d_in[10];
    float* out = (float*)d_out;

    const int N = in_sizes[0] / F_IN;
    const int E = in_sizes[2];
    const int B = (N + 1023) / 1024;

    // workspace layout (4-byte units, regions 16B-aligned)
    uint*  H2   = (uint*)d_ws;                                  // N*64
    unsigned short* T16 = (unsigned short*)(H2 + (size_t)N * F_HOP); // N*64 u16 = N*32 words
    float* dg1  = (float*)(T16 + (size_t)N * F_HOP);            // N
    int2*  ecv  = (int2*)(dg1 + (size_t)((N + 3) & ~3));        // E int2
    int*   cnt  = (int*)(ecv + (size_t)E);                      // B*1024 (zeroed)
    int*   rowptr = cnt + (size_t)B * 1024;                     // N+1
    int*   next = rowptr + (size_t)((N + 7) & ~3);              // N
    int*   part = next + (size_t)((N + 3) & ~3);                // B
    int*   poff = part + (size_t)((B + 3) & ~3);                // B

    gemm_pack_kernel<<<(N + 63) / 64, 256, 0, stream>>>(x, W0, W1, H2, N);

    zero_i4_kernel<<<(B * 1024 / 4 + 255) / 256, 256, 0, stream>>>((int4*)cnt, B * 1024 / 4);
    count_kernel<<<(E + 255) / 256, 256, 0, stream>>>(ei, cnt, E);
    reduce_kernel<<<B, 256, 0, stream>>>(cnt, part);
    scan_partials_kernel<<<1, 64, 0, stream>>>(part, poff, rowptr, B, N);
    scan_apply_kernel<<<B, 256, 0, stream>>>(cnt, poff, rowptr, next, N);
    scatter_kernel<<<(E + 255) / 256, 256, 0, stream>>>(ei, ea, next, ecv, E);

    pass1_kernel<<<(N + 3) / 4, 256, 0, stream>>>(
        rowptr, ecv, H2, b0, fc0, bf0, out, T16, dg1, N);

    pass2_kernel<<<(N + 3) / 4, 256, 0, stream>>>(
        rowptr, ecv, T16, dg1, b1, fc1, bf1, out, N);
}

// Round 4
// 338.309 us; speedup vs baseline: 2.8730x; 1.1297x over previous
//
#include <hip/hip_runtime.h>

#define F_IN 128
#define F_ALL 128
#define F_HOP 64

typedef unsigned int uint;
typedef unsigned short ushort;
typedef __attribute__((ext_vector_type(8))) short short8v;
typedef __attribute__((ext_vector_type(4))) float float4v;

// ---------------------------------------------------------------- helpers
__device__ __forceinline__ uint pack_bf16(float lo, float hi) {
    uint ul = __float_as_uint(lo), uh = __float_as_uint(hi);
    ul += 0x7FFFu + ((ul >> 16) & 1u);
    uh += 0x7FFFu + ((uh >> 16) & 1u);
    return (ul >> 16) | (uh & 0xFFFF0000u);
}
__device__ __forceinline__ float bf_lo(uint h) { return __uint_as_float(h << 16); }
__device__ __forceinline__ float bf_hi(uint h) { return __uint_as_float(h & 0xFFFF0000u); }
__device__ __forceinline__ ushort to_bf16(float x) {
    uint u = __float_as_uint(x);
    u += 0x7FFFu + ((u >> 16) & 1u);
    return (ushort)(u >> 16);
}

// ---------------------------------------------------------------- zero fill (ints)
__global__ __launch_bounds__(256) void zero_i4_kernel(int4* __restrict__ p, int n4) {
    int i = blockIdx.x * 256 + threadIdx.x;
    if (i < n4) p[i] = make_int4(0, 0, 0, 0);
}

// ---------------------------------------------------------------- MFMA GEMM + bf16 pack
// H2[r][f] = pack(bf16((x@W0)[r][f]), bf16((x@W1)[r][f])), f in 0..63.
// 256 threads = 4 waves; wave owns 16 rows x 128 cols.
// B = [W0|W1] (128x128) staged once into LDS in B-fragment order (32 KB):
//   frag(kt 0..3, nt 0..7, lane): 8 bf16 = B[kt*32 + (lane>>4)*8 + j][nt*16 + (lane&15)]
// A loaded from global x with inline RNE bf16 cvt (each row read once).
__global__ __launch_bounds__(256) void gemm_mfma_kernel(
    const float* __restrict__ x, const float* __restrict__ W0,
    const float* __restrict__ W1, uint* __restrict__ H2, int N) {
    __shared__ ushort Wlds[16384];    // 4*8*64 fragments * 8 bf16 = 32 KB

    // ---- stage B fragments (each thread: 8 fragments of 8 strided elements)
    {
        const int t = threadIdx.x;
        #pragma unroll
        for (int i = 0; i < 8; ++i) {
            const int e    = t + 256 * i;        // 0..2047
            const int lane = e & 63;
            const int tile = e >> 6;             // 0..31
            const int kt   = tile >> 3;
            const int nt   = tile & 7;
            const int k0   = kt * 32 + (lane >> 4) * 8;
            const int n    = nt * 16 + (lane & 15);
            const float* src = (n < 64) ? (W0 + n) : (W1 + (n - 64));
            float v[8];
            #pragma unroll
            for (int j = 0; j < 8; ++j) v[j] = src[(size_t)(k0 + j) * F_HOP];
            uint4 o;
            o.x = pack_bf16(v[0], v[1]);
            o.y = pack_bf16(v[2], v[3]);
            o.z = pack_bf16(v[4], v[5]);
            o.w = pack_bf16(v[6], v[7]);
            *((uint4*)Wlds + e) = o;
        }
    }
    __syncthreads();

    const int wv   = threadIdx.x >> 6;
    const int lane = threadIdx.x & 63;
    const int rbase = blockIdx.x * 64 + wv * 16;
    if (rbase >= N) return;                      // 16 | N, so no partial wave

    const int m    = lane & 15;
    const int quad = lane >> 4;
    const float* xrow = x + (size_t)(rbase + m) * F_IN + quad * 8;

    float4v acc[8];
    #pragma unroll
    for (int t = 0; t < 8; ++t) acc[t] = (float4v){0.f, 0.f, 0.f, 0.f};

    #pragma unroll
    for (int kt = 0; kt < 4; ++kt) {
        const float4 xa = *(const float4*)(xrow + kt * 32);
        const float4 xb = *(const float4*)(xrow + kt * 32 + 4);
        union { uint4 u; short8v s; } av;
        av.u.x = pack_bf16(xa.x, xa.y);
        av.u.y = pack_bf16(xa.z, xa.w);
        av.u.z = pack_bf16(xb.x, xb.y);
        av.u.w = pack_bf16(xb.z, xb.w);
        #pragma unroll
        for (int nt = 0; nt < 8; ++nt) {
            union { uint4 u; short8v s; } bv;
            bv.u = *((const uint4*)Wlds + (kt * 8 + nt) * 64 + lane);
            acc[nt] = __builtin_amdgcn_mfma_f32_16x16x32_bf16(av.s, bv.s, acc[nt], 0, 0, 0);
        }
    }

    // ---- epilogue: C/D layout col=lane&15, row=quad*4+i; pack hop0|hop1
    #pragma unroll
    for (int t = 0; t < 4; ++t) {
        #pragma unroll
        for (int i = 0; i < 4; ++i) {
            const int r = rbase + quad * 4 + i;
            H2[(size_t)r * F_HOP + t * 16 + m] = pack_bf16(acc[t][i], acc[t + 4][i]);
        }
    }
}

// ---------------------------------------------------------------- CSR build
__global__ __launch_bounds__(256) void count_kernel(
    const int* __restrict__ ei, int* __restrict__ cnt, int E) {
    const int e = blockIdx.x * 256 + threadIdx.x;
    if (e < E) atomicAdd(&cnt[ei[e]], 1);
}

__global__ __launch_bounds__(256) void reduce_kernel(
    const int* __restrict__ cnt, int* __restrict__ part) {
    __shared__ int ws[4];
    const int t = threadIdx.x;
    const int4 c = *(const int4*)(cnt + blockIdx.x * 1024 + t * 4);
    int s = c.x + c.y + c.z + c.w;
    #pragma unroll
    for (int m = 1; m < 64; m <<= 1) s += __shfl_xor(s, m, 64);
    if ((t & 63) == 0) ws[t >> 6] = s;
    __syncthreads();
    if (t == 0) part[blockIdx.x] = ws[0] + ws[1] + ws[2] + ws[3];
}

__global__ void scan_partials_kernel(const int* __restrict__ part,
                                     int* __restrict__ poff,
                                     int* __restrict__ rowptr, int B, int N) {
    if (threadIdx.x == 0 && blockIdx.x == 0) {
        int acc = 0;
        for (int i = 0; i < B; ++i) { poff[i] = acc; acc += part[i]; }
        rowptr[N] = acc;
    }
}

__global__ __launch_bounds__(256) void scan_apply_kernel(
    const int* __restrict__ cnt, const int* __restrict__ poff,
    int* __restrict__ rowptr, int* __restrict__ next, int N) {
    __shared__ int wsum[4];
    const int t = threadIdx.x;
    const int base = blockIdx.x * 1024 + t * 4;
    const int4 c = *(const int4*)(cnt + base);
    const int s = c.x + c.y + c.z + c.w;
    const int lane = t & 63;
    int v = s;
    #pragma unroll
    for (int d = 1; d < 64; d <<= 1) {
        int u = __shfl_up(v, (unsigned)d, 64);
        if (lane >= d) v += u;
    }
    const int w = t >> 6;
    if (lane == 63) wsum[w] = v;
    __syncthreads();
    int woff = 0;
    #pragma unroll
    for (int i = 0; i < 4; ++i) if (i < w) woff += wsum[i];
    const int excl = poff[blockIdx.x] + woff + (v - s);
    const int o0 = excl, o1 = o0 + c.x, o2 = o1 + c.y, o3 = o2 + c.z;
    if (base + 3 < N) {
        *(int4*)(rowptr + base) = make_int4(o0, o1, o2, o3);
        *(int4*)(next   + base) = make_int4(o0, o1, o2, o3);
    } else {
        if (base + 0 < N) { rowptr[base + 0] = o0; next[base + 0] = o0; }
        if (base + 1 < N) { rowptr[base + 1] = o1; next[base + 1] = o1; }
        if (base + 2 < N) { rowptr[base + 2] = o2; next[base + 2] = o2; }
        if (base + 3 < N) { rowptr[base + 3] = o3; next[base + 3] = o3; }
    }
}

__global__ __launch_bounds__(256) void scatter_kernel(
    const int* __restrict__ ei, const float* __restrict__ ea,
    int* __restrict__ next, int2* __restrict__ ecv, int E) {
    const int e = blockIdx.x * 256 + threadIdx.x;
    if (e >= E) return;
    const int r = ei[e];
    const int pos = atomicAdd(&next[r], 1);
    ecv[pos] = make_int2(ei[E + e], __float_as_int(ea[e]));
}

// ---------------------------------------------------------------- pass 1
__global__ __launch_bounds__(256) void pass1_kernel(
    const int* __restrict__ rowptr, const int2* __restrict__ ecv,
    const uint* __restrict__ H2,
    const float* __restrict__ b0, const float* __restrict__ fc0,
    const float* __restrict__ bf0,
    float* __restrict__ out, ushort* __restrict__ T16,
    float* __restrict__ dg1, int N) {
    int r = blockIdx.x * 4 + (threadIdx.x >> 6);
    r = __builtin_amdgcn_readfirstlane(r);
    if (r >= N) return;
    const int f = threadIdx.x & 63;
    const int jb = rowptr[r], je = rowptr[r + 1];
    float s0a = 0.f, s0b = 0.f, s0c = 0.f, s0d = 0.f;
    float s1a = 0.f, s1b = 0.f, s1c = 0.f, s1d = 0.f;
    float da = 0.f, db = 0.f;
    int j = jb;
    for (; j + 4 <= je; j += 4) {
        const int2 e0 = ecv[j], e1 = ecv[j + 1], e2 = ecv[j + 2], e3 = ecv[j + 3];
        const uint h0 = H2[(size_t)e0.x * F_HOP + f];
        const uint h1 = H2[(size_t)e1.x * F_HOP + f];
        const uint h2 = H2[(size_t)e2.x * F_HOP + f];
        const uint h3 = H2[(size_t)e3.x * F_HOP + f];
        const float v0 = __int_as_float(e0.y), v1 = __int_as_float(e1.y);
        const float v2 = __int_as_float(e2.y), v3 = __int_as_float(e3.y);
        da += v0 + v1; db += v2 + v3;
        s0a = fmaf(v0, bf_lo(h0), s0a); s1a = fmaf(v0, bf_hi(h0), s1a);
        s0b = fmaf(v1, bf_lo(h1), s0b); s1b = fmaf(v1, bf_hi(h1), s1b);
        s0c = fmaf(v2, bf_lo(h2), s0c); s1c = fmaf(v2, bf_hi(h2), s1c);
        s0d = fmaf(v3, bf_lo(h3), s0d); s1d = fmaf(v3, bf_hi(h3), s1d);
    }
    for (; j < je; ++j) {
        const int2 e0 = ecv[j];
        const uint h0 = H2[(size_t)e0.x * F_HOP + f];
        const float v0 = __int_as_float(e0.y);
        da += v0;
        s0a = fmaf(v0, bf_lo(h0), s0a); s1a = fmaf(v0, bf_hi(h0), s1a);
    }
    const float acc0 = (s0a + s0b) + (s0c + s0d);
    const float acc1 = (s1a + s1b) + (s1c + s1d);
    const float d = (da + db);
    T16[(size_t)r * F_HOP + f] = to_bf16(acc1);
    if (f == 0) dg1[r] = d;
    float y = (d > 0.f ? acc0 / d : 0.f) + b0[f];
    float t = y * fc0[f];
    #pragma unroll
    for (int m = 1; m < 64; m <<= 1) t += __shfl_xor(t, m, 64);
    const float g = 1.f / (1.f + __expf(-(t + bf0[0])));
    out[(size_t)r * F_ALL + f] = fmaxf(y, 0.f) + g * fminf(y, 0.f);
}

// ---------------------------------------------------------------- pass 2
__global__ __launch_bounds__(256) void pass2_kernel(
    const int* __restrict__ rowptr, const int2* __restrict__ ecv,
    const ushort* __restrict__ T16, const float* __restrict__ dg1,
    const float* __restrict__ b1, const float* __restrict__ fc1,
    const float* __restrict__ bf1,
    float* __restrict__ out, int N) {
    int r = blockIdx.x * 4 + (threadIdx.x >> 6);
    r = __builtin_amdgcn_readfirstlane(r);
    if (r >= N) return;
    const int f = threadIdx.x & 63;
    const int jb = rowptr[r], je = rowptr[r + 1];
    float sa = 0.f, sb = 0.f, sc = 0.f, sd = 0.f;
    float da = 0.f, db = 0.f;
    int j = jb;
    for (; j + 4 <= je; j += 4) {
        const int2 e0 = ecv[j], e1 = ecv[j + 1], e2 = ecv[j + 2], e3 = ecv[j + 3];
        const ushort t0 = T16[(size_t)e0.x * F_HOP + f];
        const ushort t1 = T16[(size_t)e1.x * F_HOP + f];
        const ushort t2 = T16[(size_t)e2.x * F_HOP + f];
        const ushort t3 = T16[(size_t)e3.x * F_HOP + f];
        const float g0 = dg1[e0.x], g1 = dg1[e1.x], g2 = dg1[e2.x], g3 = dg1[e3.x];
        const float v0 = __int_as_float(e0.y), v1 = __int_as_float(e1.y);
        const float v2 = __int_as_float(e2.y), v3 = __int_as_float(e3.y);
        da = fmaf(v0, g0, da); db = fmaf(v1, g1, db);
        da = fmaf(v2, g2, da); db = fmaf(v3, g3, db);
        sa = fmaf(v0, __uint_as_float((uint)t0 << 16), sa);
        sb = fmaf(v1, __uint_as_float((uint)t1 << 16), sb);
        sc = fmaf(v2, __uint_as_float((uint)t2 << 16), sc);
        sd = fmaf(v3, __uint_as_float((uint)t3 << 16), sd);
    }
    for (; j < je; ++j) {
        const int2 e0 = ecv[j];
        const ushort t0 = T16[(size_t)e0.x * F_HOP + f];
        const float v0 = __int_as_float(e0.y);
        da = fmaf(v0, dg1[e0.x], da);
        sa = fmaf(v0, __uint_as_float((uint)t0 << 16), sa);
    }
    const float acc = (sa + sb) + (sc + sd);
    const float d2 = da + db;
    float y = (d2 > 0.f ? acc / d2 : 0.f) + b1[f];
    float t = y * fc1[f];
    #pragma unroll
    for (int m = 1; m < 64; m <<= 1) t += __shfl_xor(t, m, 64);
    const float g = 1.f / (1.f + __expf(-(t + bf1[0])));
    out[(size_t)r * F_ALL + F_HOP + f] = fmaxf(y, 0.f) + g * fminf(y, 0.f);
}

// ---------------------------------------------------------------- launch
extern "C" void kernel_launch(void* const* d_in, const int* in_sizes, int n_in,
                              void* d_out, int out_size, void* d_ws, size_t ws_size,
                              hipStream_t stream) {
    const float* x   = (const float*)d_in[0];
    const int*   ei  = (const int*)  d_in[1];
    const float* ea  = (const float*)d_in[2];
    const float* W0  = (const float*)d_in[3];
    const float* b0  = (const float*)d_in[4];
    const float* W1  = (const float*)d_in[5];
    const float* b1  = (const float*)d_in[6];
    const float* fc0 = (const float*)d_in[7];
    const float* bf0 = (const float*)d_in[8];
    const float* fc1 = (const float*)d_in[9];
    const float* bf1 = (const float*)d_in[10];
    float* out = (float*)d_out;

    const int N = in_sizes[0] / F_IN;
    const int E = in_sizes[2];
    const int B = (N + 1023) / 1024;

    // workspace layout (4-byte units, regions 16B-aligned)
    uint*  H2   = (uint*)d_ws;                                  // N*64
    ushort* T16 = (ushort*)(H2 + (size_t)N * F_HOP);            // N*64 u16
    float* dg1  = (float*)(T16 + (size_t)N * F_HOP);            // N
    int2*  ecv  = (int2*)(dg1 + (size_t)((N + 3) & ~3));        // E int2
    int*   cnt  = (int*)(ecv + (size_t)E);                      // B*1024 (zeroed)
    int*   rowptr = cnt + (size_t)B * 1024;                     // N+1
    int*   next = rowptr + (size_t)((N + 7) & ~3);              // N
    int*   part = next + (size_t)((N + 3) & ~3);                // B
    int*   poff = part + (size_t)((B + 3) & ~3);                // B

    gemm_mfma_kernel<<<(N + 63) / 64, 256, 0, stream>>>(x, W0, W1, H2, N);

    zero_i4_kernel<<<(B * 1024 / 4 + 255) / 256, 256, 0, stream>>>((int4*)cnt, B * 1024 / 4);
    count_kernel<<<(E + 255) / 256, 256, 0, stream>>>(ei, cnt, E);
    reduce_kernel<<<B, 256, 0, stream>>>(cnt, part);
    scan_partials_kernel<<<1, 64, 0, stream>>>(part, poff, rowptr, B, N);
    scan_apply_kernel<<<B, 256, 0, stream>>>(cnt, poff, rowptr, next, N);
    scatter_kernel<<<(E + 255) / 256, 256, 0, stream>>>(ei, ea, next, ecv, E);

    pass1_kernel<<<(N + 3) / 4, 256, 0, stream>>>(
        rowptr, ecv, H2, b0, fc0, bf0, out, T16, dg1, N);

    pass2_kernel<<<(N + 3) / 4, 256, 0, stream>>>(
        rowptr, ecv, T16, dg1, b1, fc1, bf1, out, N);
}

// Round 5
// 338.001 us; speedup vs baseline: 2.8756x; 1.0009x over previous
//
#include <hip/hip_runtime.h>

#define F_IN 128
#define F_ALL 128
#define F_HOP 64

#define RPB_BITS 9
#define RPB 512            // rows per bucket
#define KB_MAX 256         // max buckets (N <= 131072)
#define NBLK_BIN 128       // blocks for hist/bin kernels
#define BCAP 16            // LDS slots per bucket in bin kernel

typedef unsigned int uint;
typedef unsigned short ushort;
typedef __attribute__((ext_vector_type(8))) short short8v;
typedef __attribute__((ext_vector_type(4))) float float4v;

// ---------------------------------------------------------------- helpers
__device__ __forceinline__ uint pack_bf16(float lo, float hi) {
    uint ul = __float_as_uint(lo), uh = __float_as_uint(hi);
    ul += 0x7FFFu + ((ul >> 16) & 1u);
    uh += 0x7FFFu + ((uh >> 16) & 1u);
    return (ul >> 16) | (uh & 0xFFFF0000u);
}
__device__ __forceinline__ float bf_lo(uint h) { return __uint_as_float(h << 16); }
__device__ __forceinline__ float bf_hi(uint h) { return __uint_as_float(h & 0xFFFF0000u); }
__device__ __forceinline__ ushort to_bf16(float x) {
    uint u = __float_as_uint(x);
    u += 0x7FFFu + ((u >> 16) & 1u);
    return (ushort)(u >> 16);
}

// ---------------------------------------------------------------- MFMA GEMM + bf16 pack
__global__ __launch_bounds__(256) void gemm_mfma_kernel(
    const float* __restrict__ x, const float* __restrict__ W0,
    const float* __restrict__ W1, uint* __restrict__ H2, int N) {
    __shared__ ushort Wlds[16384];    // 4*8*64 fragments * 8 bf16 = 32 KB

    {
        const int t = threadIdx.x;
        #pragma unroll
        for (int i = 0; i < 8; ++i) {
            const int e    = t + 256 * i;
            const int lane = e & 63;
            const int tile = e >> 6;
            const int kt   = tile >> 3;
            const int nt   = tile & 7;
            const int k0   = kt * 32 + (lane >> 4) * 8;
            const int n    = nt * 16 + (lane & 15);
            const float* src = (n < 64) ? (W0 + n) : (W1 + (n - 64));
            float v[8];
            #pragma unroll
            for (int j = 0; j < 8; ++j) v[j] = src[(size_t)(k0 + j) * F_HOP];
            uint4 o;
            o.x = pack_bf16(v[0], v[1]);
            o.y = pack_bf16(v[2], v[3]);
            o.z = pack_bf16(v[4], v[5]);
            o.w = pack_bf16(v[6], v[7]);
            *((uint4*)Wlds + e) = o;
        }
    }
    __syncthreads();

    const int wv   = threadIdx.x >> 6;
    const int lane = threadIdx.x & 63;
    const int rbase = blockIdx.x * 64 + wv * 16;
    if (rbase >= N) return;

    const int m    = lane & 15;
    const int quad = lane >> 4;
    const float* xrow = x + (size_t)(rbase + m) * F_IN + quad * 8;

    float4v acc[8];
    #pragma unroll
    for (int t = 0; t < 8; ++t) acc[t] = (float4v){0.f, 0.f, 0.f, 0.f};

    #pragma unroll
    for (int kt = 0; kt < 4; ++kt) {
        const float4 xa = *(const float4*)(xrow + kt * 32);
        const float4 xb = *(const float4*)(xrow + kt * 32 + 4);
        union { uint4 u; short8v s; } av;
        av.u.x = pack_bf16(xa.x, xa.y);
        av.u.y = pack_bf16(xa.z, xa.w);
        av.u.z = pack_bf16(xb.x, xb.y);
        av.u.w = pack_bf16(xb.z, xb.w);
        #pragma unroll
        for (int nt = 0; nt < 8; ++nt) {
            union { uint4 u; short8v s; } bv;
            bv.u = *((const uint4*)Wlds + (kt * 8 + nt) * 64 + lane);
            acc[nt] = __builtin_amdgcn_mfma_f32_16x16x32_bf16(av.s, bv.s, acc[nt], 0, 0, 0);
        }
    }

    #pragma unroll
    for (int t = 0; t < 4; ++t) {
        #pragma unroll
        for (int i = 0; i < 4; ++i) {
            const int r = rbase + quad * 4 + i;
            H2[(size_t)r * F_HOP + t * 16 + m] = pack_bf16(acc[t][i], acc[t + 4][i]);
        }
    }
}

// ---------------------------------------------------------------- CSR build, stage 1: bucket histogram
// per-block LDS hist over K coarse buckets -> per-block partial rows (no atomics, no pre-zero)
__global__ __launch_bounds__(256) void bucket_hist_kernel(
    const int* __restrict__ ei, int* __restrict__ bhist, int E, int K) {
    __shared__ int h[KB_MAX];
    for (int i = threadIdx.x; i < K; i += 256) h[i] = 0;
    __syncthreads();
    const int chunk = (E + NBLK_BIN - 1) / NBLK_BIN;
    const int s = blockIdx.x * chunk;
    const int e = min(s + chunk, E);
    for (int j = s + threadIdx.x; j < e; j += 256)
        atomicAdd(&h[ei[j] >> RPB_BITS], 1);
    __syncthreads();
    for (int i = threadIdx.x; i < K; i += 256)
        bhist[blockIdx.x * KB_MAX + i] = h[i];
}

// ---------------------------------------------------------------- stage 2: scan bucket totals (1 block)
__global__ __launch_bounds__(256) void bucket_scan_kernel(
    const int* __restrict__ bhist, int* __restrict__ bbase,
    int* __restrict__ gnext, int* __restrict__ rowptr, int E, int K, int N) {
    __shared__ int wsum[4];
    const int t = threadIdx.x;
    int s = 0;
    if (t < K)
        for (int i = 0; i < NBLK_BIN; ++i) s += bhist[i * KB_MAX + t];
    int v = s;
    #pragma unroll
    for (int d = 1; d < 64; d <<= 1) {
        int u = __shfl_up(v, (unsigned)d, 64);
        if ((t & 63) >= d) v += u;
    }
    if ((t & 63) == 63) wsum[t >> 6] = v;
    __syncthreads();
    int off = 0;
    #pragma unroll
    for (int i = 0; i < 4; ++i) if (i < (t >> 6)) off += wsum[i];
    const int excl = off + v - s;
    if (t < K) { bbase[t] = excl; gnext[t] = excl; }
    if (t == 0) { bbase[K] = E; rowptr[N] = E; }
}

// ---------------------------------------------------------------- stage 3: binned scatter (phase A)
// LDS-staged per-bucket accumulation, flushed in contiguous runs of 8 (64 B appends).
// payload: word0 = col | (r_local << 17), word1 = val fp32
__global__ __launch_bounds__(256) void bin_kernel(
    const int* __restrict__ ei, const float* __restrict__ ea,
    int* __restrict__ gnext, int2* __restrict__ gbuf, int E, int K) {
    __shared__ int buf[KB_MAX * (2 * BCAP + 1)];  // stride 33 ints: odd -> 2-way-max bank aliasing
    __shared__ int lcnt[KB_MAX];
    for (int i = threadIdx.x; i < K; i += 256) lcnt[i] = 0;
    __syncthreads();
    const int chunk = (E + NBLK_BIN - 1) / NBLK_BIN;
    const int s0 = blockIdx.x * chunk;
    const int e0 = min(s0 + chunk, E);
    for (int base = s0; base < e0; base += 256) {
        const int j = base + threadIdx.x;
        if (j < e0) {
            const int r = ei[j];
            const int c = ei[E + j];
            const int vv = __float_as_int(ea[j]);
            const int b = r >> RPB_BITS;
            const int w0 = c | ((r & (RPB - 1)) << 17);
            const int pos = atomicAdd(&lcnt[b], 1);
            if (pos < BCAP) {
                const int boff = b * (2 * BCAP + 1) + 2 * pos;
                buf[boff] = w0; buf[boff + 1] = vv;
            } else {
                const int gp = atomicAdd(&gnext[b], 1);
                gbuf[gp] = make_int2(w0, vv);
            }
        }
        __syncthreads();
        for (int b = threadIdx.x; b < K; b += 256) {
            int c = lcnt[b]; if (c > BCAP) c = BCAP;
            if (c >= 8) {
                const int n = c & ~7;
                const int gp = atomicAdd(&gnext[b], n);
                const int boff = b * (2 * BCAP + 1);
                for (int i = 0; i < n; ++i)
                    gbuf[gp + i] = make_int2(buf[boff + 2 * i], buf[boff + 2 * i + 1]);
                for (int i = n; i < c; ++i) {
                    buf[boff + 2 * (i - n)]     = buf[boff + 2 * i];
                    buf[boff + 2 * (i - n) + 1] = buf[boff + 2 * i + 1];
                }
                lcnt[b] = c - n;
            } else {
                lcnt[b] = c;
            }
        }
        __syncthreads();
    }
    for (int b = threadIdx.x; b < K; b += 256) {
        int c = lcnt[b]; if (c > BCAP) c = BCAP;
        if (c > 0) {
            const int gp = atomicAdd(&gnext[b], c);
            const int boff = b * (2 * BCAP + 1);
            for (int i = 0; i < c; ++i)
                gbuf[gp + i] = make_int2(buf[boff + 2 * i], buf[boff + 2 * i + 1]);
        }
    }
}

// ---------------------------------------------------------------- stage 4: per-bucket sort (phase B)
// one block per bucket: LDS count -> LDS scan -> place. Random writes stay in the
// bucket's ~40 KB L2-resident window. Also emits rowptr for the bucket's rows.
__global__ __launch_bounds__(256) void sort_kernel(
    const int* __restrict__ bbase, const int2* __restrict__ gbuf,
    int2* __restrict__ ecv, int* __restrict__ rowptr, int N) {
    __shared__ int cnt[RPB];
    __shared__ int nxt[RPB];
    __shared__ int wsum[4];
    const int b = blockIdx.x;
    const int t = threadIdx.x;
    const int bstart = bbase[b], bend = bbase[b + 1];
    const int row0 = b << RPB_BITS;
    for (int i = t; i < RPB; i += 256) cnt[i] = 0;
    __syncthreads();
    for (int j = bstart + t; j < bend; j += 256)
        atomicAdd(&cnt[(gbuf[j].x >> 17) & (RPB - 1)], 1);
    __syncthreads();
    const int c0 = cnt[2 * t], c1 = cnt[2 * t + 1];
    const int s = c0 + c1;
    int v = s;
    #pragma unroll
    for (int d = 1; d < 64; d <<= 1) {
        int u = __shfl_up(v, (unsigned)d, 64);
        if ((t & 63) >= d) v += u;
    }
    if ((t & 63) == 63) wsum[t >> 6] = v;
    __syncthreads();
    int off = 0;
    #pragma unroll
    for (int i = 0; i < 4; ++i) if (i < (t >> 6)) off += wsum[i];
    const int e0 = off + v - s;           // exclusive over row pairs
    nxt[2 * t]     = e0;
    nxt[2 * t + 1] = e0 + c0;
    const int r0 = row0 + 2 * t, r1 = row0 + 2 * t + 1;
    if (r0 < N) rowptr[r0] = bstart + e0;
    if (r1 < N) rowptr[r1] = bstart + e0 + c0;
    __syncthreads();
    for (int j = bstart + t; j < bend; j += 256) {
        const int2 p = gbuf[j];
        const int lr = (p.x >> 17) & (RPB - 1);
        const int pos = atomicAdd(&nxt[lr], 1);
        ecv[bstart + pos] = make_int2(p.x & 0x1FFFF, p.y);
    }
}

// ---------------------------------------------------------------- pass 1
__global__ __launch_bounds__(256) void pass1_kernel(
    const int* __restrict__ rowptr, const int2* __restrict__ ecv,
    const uint* __restrict__ H2,
    const float* __restrict__ b0, const float* __restrict__ fc0,
    const float* __restrict__ bf0,
    float* __restrict__ out, ushort* __restrict__ T16,
    float* __restrict__ dg1, int N) {
    int r = blockIdx.x * 4 + (threadIdx.x >> 6);
    r = __builtin_amdgcn_readfirstlane(r);
    if (r >= N) return;
    const int f = threadIdx.x & 63;
    const int jb = rowptr[r], je = rowptr[r + 1];
    float s0a = 0.f, s0b = 0.f, s0c = 0.f, s0d = 0.f;
    float s1a = 0.f, s1b = 0.f, s1c = 0.f, s1d = 0.f;
    float da = 0.f, db = 0.f;
    int j = jb;
    for (; j + 4 <= je; j += 4) {
        const int2 e0 = ecv[j], e1 = ecv[j + 1], e2 = ecv[j + 2], e3 = ecv[j + 3];
        const uint h0 = H2[(size_t)e0.x * F_HOP + f];
        const uint h1 = H2[(size_t)e1.x * F_HOP + f];
        const uint h2 = H2[(size_t)e2.x * F_HOP + f];
        const uint h3 = H2[(size_t)e3.x * F_HOP + f];
        const float v0 = __int_as_float(e0.y), v1 = __int_as_float(e1.y);
        const float v2 = __int_as_float(e2.y), v3 = __int_as_float(e3.y);
        da += v0 + v1; db += v2 + v3;
        s0a = fmaf(v0, bf_lo(h0), s0a); s1a = fmaf(v0, bf_hi(h0), s1a);
        s0b = fmaf(v1, bf_lo(h1), s0b); s1b = fmaf(v1, bf_hi(h1), s1b);
        s0c = fmaf(v2, bf_lo(h2), s0c); s1c = fmaf(v2, bf_hi(h2), s1c);
        s0d = fmaf(v3, bf_lo(h3), s0d); s1d = fmaf(v3, bf_hi(h3), s1d);
    }
    for (; j < je; ++j) {
        const int2 e0 = ecv[j];
        const uint h0 = H2[(size_t)e0.x * F_HOP + f];
        const float v0 = __int_as_float(e0.y);
        da += v0;
        s0a = fmaf(v0, bf_lo(h0), s0a); s1a = fmaf(v0, bf_hi(h0), s1a);
    }
    const float acc0 = (s0a + s0b) + (s0c + s0d);
    const float acc1 = (s1a + s1b) + (s1c + s1d);
    const float d = (da + db);
    T16[(size_t)r * F_HOP + f] = to_bf16(acc1);
    if (f == 0) dg1[r] = d;
    float y = (d > 0.f ? acc0 / d : 0.f) + b0[f];
    float t = y * fc0[f];
    #pragma unroll
    for (int m = 1; m < 64; m <<= 1) t += __shfl_xor(t, m, 64);
    const float g = 1.f / (1.f + __expf(-(t + bf0[0])));
    out[(size_t)r * F_ALL + f] = fmaxf(y, 0.f) + g * fminf(y, 0.f);
}

// ---------------------------------------------------------------- pass 2
__global__ __launch_bounds__(256) void pass2_kernel(
    const int* __restrict__ rowptr, const int2* __restrict__ ecv,
    const ushort* __restrict__ T16, const float* __restrict__ dg1,
    const float* __restrict__ b1, const float* __restrict__ fc1,
    const float* __restrict__ bf1,
    float* __restrict__ out, int N) {
    int r = blockIdx.x * 4 + (threadIdx.x >> 6);
    r = __builtin_amdgcn_readfirstlane(r);
    if (r >= N) return;
    const int f = threadIdx.x & 63;
    const int jb = rowptr[r], je = rowptr[r + 1];
    float sa = 0.f, sb = 0.f, sc = 0.f, sd = 0.f;
    float da = 0.f, db = 0.f;
    int j = jb;
    for (; j + 4 <= je; j += 4) {
        const int2 e0 = ecv[j], e1 = ecv[j + 1], e2 = ecv[j + 2], e3 = ecv[j + 3];
        const ushort t0 = T16[(size_t)e0.x * F_HOP + f];
        const ushort t1 = T16[(size_t)e1.x * F_HOP + f];
        const ushort t2 = T16[(size_t)e2.x * F_HOP + f];
        const ushort t3 = T16[(size_t)e3.x * F_HOP + f];
        const float g0 = dg1[e0.x], g1 = dg1[e1.x], g2 = dg1[e2.x], g3 = dg1[e3.x];
        const float v0 = __int_as_float(e0.y), v1 = __int_as_float(e1.y);
        const float v2 = __int_as_float(e2.y), v3 = __int_as_float(e3.y);
        da = fmaf(v0, g0, da); db = fmaf(v1, g1, db);
        da = fmaf(v2, g2, da); db = fmaf(v3, g3, db);
        sa = fmaf(v0, __uint_as_float((uint)t0 << 16), sa);
        sb = fmaf(v1, __uint_as_float((uint)t1 << 16), sb);
        sc = fmaf(v2, __uint_as_float((uint)t2 << 16), sc);
        sd = fmaf(v3, __uint_as_float((uint)t3 << 16), sd);
    }
    for (; j < je; ++j) {
        const int2 e0 = ecv[j];
        const ushort t0 = T16[(size_t)e0.x * F_HOP + f];
        const float v0 = __int_as_float(e0.y);
        da = fmaf(v0, dg1[e0.x], da);
        sa = fmaf(v0, __uint_as_float((uint)t0 << 16), sa);
    }
    const float acc = (sa + sb) + (sc + sd);
    const float d2 = da + db;
    float y = (d2 > 0.f ? acc / d2 : 0.f) + b1[f];
    float t = y * fc1[f];
    #pragma unroll
    for (int m = 1; m < 64; m <<= 1) t += __shfl_xor(t, m, 64);
    const float g = 1.f / (1.f + __expf(-(t + bf1[0])));
    out[(size_t)r * F_ALL + F_HOP + f] = fmaxf(y, 0.f) + g * fminf(y, 0.f);
}

// ---------------------------------------------------------------- launch
extern "C" void kernel_launch(void* const* d_in, const int* in_sizes, int n_in,
                              void* d_out, int out_size, void* d_ws, size_t ws_size,
                              hipStream_t stream) {
    const float* x   = (const float*)d_in[0];
    const int*   ei  = (const int*)  d_in[1];
    const float* ea  = (const float*)d_in[2];
    const float* W0  = (const float*)d_in[3];
    const float* b0  = (const float*)d_in[4];
    const float* W1  = (const float*)d_in[5];
    const float* b1  = (const float*)d_in[6];
    const float* fc0 = (const float*)d_in[7];
    const float* bf0 = (const float*)d_in[8];
    const float* fc1 = (const float*)d_in[9];
    const float* bf1 = (const float*)d_in[10];
    float* out = (float*)d_out;

    const int N = in_sizes[0] / F_IN;
    const int E = in_sizes[2];
    const int K = (N + RPB - 1) >> RPB_BITS;   // coarse buckets (<= KB_MAX)

    // workspace layout (4-byte units, regions 16B-aligned)
    uint*   H2   = (uint*)d_ws;                                  // N*64
    ushort* T16  = (ushort*)(H2 + (size_t)N * F_HOP);            // N*64 u16
    float*  dg1  = (float*)(T16 + (size_t)N * F_HOP);            // N
    int2*   gbuf = (int2*)(dg1 + (size_t)((N + 3) & ~3));        // E (bucketed edges)
    int2*   ecv  = gbuf + (size_t)E;                             // E (row-sorted edges)
    int*    bhist = (int*)(ecv + (size_t)E);                     // NBLK_BIN*KB_MAX
    int*    bbase = bhist + (size_t)NBLK_BIN * KB_MAX;           // K+1
    int*    gnext = bbase + (KB_MAX + 4);                        // K
    int*    rowptr = gnext + KB_MAX;                             // N+1

    gemm_mfma_kernel<<<(N + 63) / 64, 256, 0, stream>>>(x, W0, W1, H2, N);

    bucket_hist_kernel<<<NBLK_BIN, 256, 0, stream>>>(ei, bhist, E, K);
    bucket_scan_kernel<<<1, 256, 0, stream>>>(bhist, bbase, gnext, rowptr, E, K, N);
    bin_kernel<<<NBLK_BIN, 256, 0, stream>>>(ei, ea, gnext, gbuf, E, K);
    sort_kernel<<<K, 256, 0, stream>>>(bbase, gbuf, ecv, rowptr, N);

    pass1_kernel<<<(N + 3) / 4, 256, 0, stream>>>(
        rowptr, ecv, H2, b0, fc0, bf0, out, T16, dg1, N);

    pass2_kernel<<<(N + 3) / 4, 256, 0, stream>>>(
        rowptr, ecv, T16, dg1, b1, fc1, bf1, out, N);
}